// Round 16
// baseline (99.313 us; speedup 1.0000x reference)
//
#include <hip/hip_runtime.h>
#include <hip/hip_bf16.h>

// DiffAlphaSplitModel: VOCAB=64, H=64, HALF=32, B=256, L=2048.
//  DUAL-SPACE per-position recurrence (lane = vocab v):
//    d = gf[t_p];  e = c_p d;  gf -= e*G[:,t_p];  W[t_p] += e
//    r = sum_v W_v h_v at the end.
//  ROUND-16: kill the VALU<->SGPR hazards on the chain + halve its length.
//   r15 falsified TLP (healthy codegen, 2 waves/SIMD, still slower than r9):
//   the wall IS per-step chain latency (~83cy), dominated by two
//   VALU<->SGPR crossings per step (readlane writeback + lane-select).
//   (a) ds_bpermute with UNIFORM address broadcasts gf[t] to all lanes
//       VGPR->VGPR: no SGPR on the chain at all.
//   (b) PAIR step: both positions read the same pre-pair gf (2 bpermutes,
//       one wait); exact coupling restored via gamma = G[t_lo,t_hi]
//       = bperm(cg_hi, t_lo), gathered off-chain in the batch phase.
//   Chain/pair ~= lgkm wait + 4 VALU + 2 fmac ~= 27 cy/pos (vs 83).
//  Geometry: r9's best (256 blocks x 128 = 2 waves, 1 wave/SIMD).
//
// ws layout (floats):
//   [0     ..  4095] compact k [2][64][32]
//   [4096  ..  8191] compact h [2][64][32]
//   [16384 .. 24575] Gram [2][64][64]
//   [24576 .. 40959] rbuf [256][64]

#define L_SEQ 2048
#define NPOS  2047

__device__ __forceinline__ float rdlane(float v, int l) {
    return __int_as_float(__builtin_amdgcn_readlane(__float_as_int(v), l));
}
__device__ __forceinline__ float bperm(int byteaddr, float v) {
    return __int_as_float(__builtin_amdgcn_ds_bpermute(byteaddr, __float_as_int(v)));
}

// ---------------- Kernel A: per-vocab tables -------------------------------
__global__ void build_tables(const float* __restrict__ embed,
                             const float* __restrict__ w1, const float* __restrict__ b1,
                             const float* __restrict__ w2, const float* __restrict__ b2,
                             const float* __restrict__ ln_g, const float* __restrict__ ln_b,
                             const float* __restrict__ ws, const float* __restrict__ bs,
                             const float* __restrict__ we, const float* __restrict__ be,
                             float* __restrict__ tabs) {
    const int v = blockIdx.x;
    const int t = threadIdx.x;        // 0..63
    __shared__ float sh_h[64];
    __shared__ float sh_a[128];
    __shared__ float sh_x[64];

    sh_h[t] = embed[v * 64 + t];
    __syncthreads();

    float acc0 = b1[t], acc1 = b1[t + 64];
    #pragma unroll 8
    for (int k = 0; k < 64; ++k) {
        const float hv = sh_h[k];
        acc0 += hv * w1[k * 128 + t];
        acc1 += hv * w1[k * 128 + t + 64];
    }
    sh_a[t]      = fmaxf(acc0, 0.f);
    sh_a[t + 64] = fmaxf(acc1, 0.f);
    __syncthreads();

    float x = sh_h[t] + b2[t];
    #pragma unroll 8
    for (int k = 0; k < 128; ++k) x += sh_a[k] * w2[k * 64 + t];

    float mu = x;
    for (int m = 1; m <= 32; m <<= 1) mu += __shfl_xor(mu, m);
    mu *= (1.f / 64.f);
    const float dx = x - mu;
    float var = dx * dx;
    for (int m = 1; m <= 32; m <<= 1) var += __shfl_xor(var, m);
    var *= (1.f / 64.f);
    const float hln = dx * rsqrtf(var + 1e-5f) * ln_g[t] + ln_b[t];
    sh_x[t] = hln;
    __syncthreads();

    const int j   = t & 31;
    const int mem = t >> 5;
    const float* W  = mem ? we : ws;
    const float* Bv = mem ? be : bs;
    float p = Bv[j];
    #pragma unroll 8
    for (int k = 0; k < 64; ++k) p += sh_x[k] * W[k * 32 + j];

    float nn = p * p;
    for (int m = 1; m <= 16; m <<= 1) nn += __shfl_xor(nn, m);
    const float kn = p / fmaxf(sqrtf(nn), 1e-12f);

    tabs[(mem * 64 + v) * 32 + j]        = kn;   // normalized key
    tabs[4096 + (mem * 64 + v) * 32 + j] = p;    // raw projection
}

// ---------------- Kernel A2: Gram tables -----------------------------------
__global__ void gram_kernel(const float* __restrict__ tabs, float* __restrict__ gout) {
    const int v  = blockIdx.x;
    const int tt = threadIdx.x;          // 0..127
    const int m  = tt >> 6, w = tt & 63;
    __shared__ float kv[64];
    if (tt < 64) kv[tt] = tabs[((tt >> 5) * 64 + v) * 32 + (tt & 31)];
    __syncthreads();
    const float* kw  = &tabs[(m * 64 + w) * 32];
    const float* kvm = &kv[m * 32];
    float acc = 0.f;
    #pragma unroll 8
    for (int j = 0; j < 32; ++j) acc += kvm[j] * kw[j];
    gout[m * 4096 + v * 64 + w] = acc;
}

// ---------------- Kernel B: dual-space scan, paired bpermute chain ---------
// grid 256 (batch), block 128 = 2 waves. wave 0: s-chain, wave 1: e-chain.
// lane (0..63) = vocab id v for gf / W.
__global__ void __launch_bounds__(128, 1) scan_kernel(const int* __restrict__ seq,
                                                      const float* __restrict__ tabs,
                                                      float* __restrict__ rbuf) {
    const int b    = blockIdx.x;
    const int tid  = threadIdx.x;        // 0..127
    const int m    = tid >> 6;           // wave id == chain id
    const int lane = tid & 63;           // vocab id v
    const int q    = lane & 31;

    __shared__ float gt [2 * 64 * 65];   // Gram rows padded to 65
    __shared__ float hsh[2 * 64 * 32];   // h tables [m][v][j]

    // ---- stage (one-time) ----
    for (int i = tid; i < 8192; i += 128) {
        const int mm = i >> 12, v = (i >> 6) & 63, ww = i & 63;
        gt[mm * 4160 + v * 65 + ww] = tabs[16384 + i];
    }
    for (int i = tid; i < 1024; i += 128)
        ((float4*)hsh)[i] = ((const float4*)(tabs + 4096))[i];
    __syncthreads();

    const int*  srow  = seq + b * L_SEQ;        // uniform base -> s_load
    const int   rowV  = m * 4160 + lane * 65;   // per-lane G row base
    const float invL  = 1.0f / (float)L_SEQ;
    const bool  mF    = (m != 0);
    const float invLe = mF ? invL : 0.0f;       // c step (0 for s-chain)

    // init: u = k_tokL  =>  gf_v = G[v][tokL]
    const int tokL = srow[NPOS];
    float gf = gt[rowV + tokL];
    float W  = 0.f;

    // ---- blocks: pb = 2016, 1984, ..., 0  (64 blocks x 32 positions) ----
    // Block pb covers positions pb..pb+31; position 2047 (j=31 of pb=2016)
    // neutralized with c=0 (e=0 kills its gf/W updates and its coupling).
    for (int pb = 2016; pb >= 0; pb -= 32) {
        if (__all(fabsf(gf) < 1e-4f)) break;    // residual-based exit (per wave)

        // ---- batch: tokens (SGPR), G-columns, pair gammas, c values ----
        int tk[32];
        #pragma unroll
        for (int j = 0; j < 32; ++j) tk[j] = srow[pb + j];

        float cg[32];
        #pragma unroll
        for (int j = 0; j < 32; ++j) cg[j] = gt[rowV + tk[j]];

        // pair gammas: ga[k] = G[t_lo, t_hi] = bperm(cg_hi, t_lo) (broadcast)
        float ga[16];
        #pragma unroll
        for (int k = 0; k < 16; ++k)
            ga[k] = bperm(tk[2*k] << 2, cg[2*k + 1]);

        const float cb = mF ? (float)(pb + 1) * invL : 1.0f;
        float cc[32];
        #pragma unroll
        for (int j = 0; j < 32; ++j) cc[j] = cb + (float)j * invLe;
        if (pb == 2016) cc[31] = 0.f;           // position 2047: no update

        __builtin_amdgcn_sched_barrier(0);

        // ---- chain: 16 pair-steps, backward (k=15 first) ----
        #pragma unroll
        for (int k = 15; k >= 0; --k) {
            const int jh = 2*k + 1, jl = 2*k;
            // both reads from the SAME pre-pair gf (VGPR->VGPR broadcast)
            const float bh = bperm(tk[jh] << 2, gf);
            const float bl = bperm(tk[jl] << 2, gf);
            const float eh = cc[jh] * bh;
            const float dl = fmaf(-ga[k], eh, bl);   // exact coupling fix
            const float el = cc[jl] * dl;
            gf = fmaf(-eh, cg[jh], gf);
            gf = fmaf(-el, cg[jl], gf);
            W += (lane == tk[jh]) ? eh : 0.f;
            W += (lane == tk[jl]) ? el : 0.f;
        }
    }

    // ---- final: r_q = sum_v W_v * h[v][q] ----
    float r = 0.f;
    #pragma unroll 8
    for (int v = 0; v < 64; ++v) {
        const float wv = rdlane(W, v);
        r = fmaf(wv, hsh[(m * 64 + v) * 32 + q], r);
    }

    if (lane < 32)
        rbuf[b * 64 + m * 32 + q] = r;   // [rs | re] = concat order
}

// ---------------- Kernel C: output projection ------------------------------
__global__ void out_kernel(const float* __restrict__ rbuf,
                           const float* __restrict__ wrp, const float* __restrict__ brp,
                           const float* __restrict__ wout, const float* __restrict__ bout,
                           float* __restrict__ out) {
    const int b = blockIdx.x;
    const int t = threadIdx.x;
    __shared__ float rsh[64];
    __shared__ float ysh[64];

    rsh[t] = rbuf[b * 64 + t];
    __syncthreads();

    float y = brp[t];
    #pragma unroll 8
    for (int k = 0; k < 64; ++k) y += rsh[k] * wrp[k * 64 + t];
    ysh[t] = y;
    __syncthreads();

    float o = bout[t];
    #pragma unroll 8
    for (int k = 0; k < 64; ++k) o += ysh[k] * wout[k * 64 + t];
    out[b * 64 + t] = o;
}

// ---------------- launch ----------------------------------------------------
extern "C" void kernel_launch(void* const* d_in, const int* in_sizes, int n_in,
                              void* d_out, int out_size, void* d_ws, size_t ws_size,
                              hipStream_t stream) {
    const int*   seq   = (const int*)  d_in[0];
    const float* embed = (const float*)d_in[1];
    const float* w1    = (const float*)d_in[2];
    const float* b1    = (const float*)d_in[3];
    const float* w2    = (const float*)d_in[4];
    const float* b2    = (const float*)d_in[5];
    const float* ln_g  = (const float*)d_in[6];
    const float* ln_b  = (const float*)d_in[7];
    const float* ws    = (const float*)d_in[8];
    const float* bs    = (const float*)d_in[9];
    const float* we    = (const float*)d_in[10];
    const float* be    = (const float*)d_in[11];
    const float* wrp   = (const float*)d_in[12];
    const float* brp   = (const float*)d_in[13];
    const float* wout  = (const float*)d_in[14];
    const float* bout  = (const float*)d_in[15];

    float* tabs = (float*)d_ws;              // tables + gram
    float* gout = tabs + 16384;              // gram [2][64][64]
    float* rbuf = tabs + 24576;              // r vectors [256][64]

    build_tables<<<64, 64, 0, stream>>>(embed, w1, b1, w2, b2, ln_g, ln_b,
                                        ws, bs, we, be, tabs);
    gram_kernel<<<64, 128, 0, stream>>>(tabs, gout);
    scan_kernel<<<256, 128, 0, stream>>>(seq, tabs, rbuf);
    out_kernel<<<256, 64, 0, stream>>>(rbuf, wrp, brp, wout, bout, (float*)d_out);
}

// Round 17
// 88.320 us; speedup vs baseline: 1.1245x; 1.1245x over previous
//
#include <hip/hip_runtime.h>
#include <hip/hip_bf16.h>

// DiffAlphaSplitModel: VOCAB=64, H=64, HALF=32, B=256, L=2048.
//  DUAL-SPACE per-position recurrence (lane = vocab v):
//    d = gf[t_p] (readlane);  gf -= d * (c_p*G[:,t_p]);  W[t_p] += c_p*d
//    r = sum_v W_v h_v at the end.
//  ROUND-17 (r9 config + two subtractive tweaks):
//   - G-columns PRESCALED by c_j in the batch (cgp): chain is now
//     rdlane -> fmac only (r9 had rdlane -> mul -> fmac). e for the W
//     histogram is computed off the critical path.
//   - output projection fused into the scan epilogue (r -> LDS -> 2-stage
//     64x64 matvec); out_kernel launch and rbuf round-trip deleted.
//  History: r10-r16 tried SGPR tokens, in-order-DS pipelining, quad solve,
//  TLP (2 and 4 waves/SIMD, healthy codegen), bpermute pairs — ALL lose to
//  or match r9's simple chain (~82cy/pos). Only removing dependent ops
//  from the chain has ever helped.
//
// ws layout (floats):
//   [0     ..  4095] compact k [2][64][32]
//   [4096  ..  8191] compact h [2][64][32]
//   [16384 .. 24575] Gram [2][64][64]

#define L_SEQ 2048
#define NPOS  2047

__device__ __forceinline__ float rdlane(float v, int l) {
    return __int_as_float(__builtin_amdgcn_readlane(__float_as_int(v), l));
}

// ---------------- Kernel A: per-vocab tables -------------------------------
__global__ void build_tables(const float* __restrict__ embed,
                             const float* __restrict__ w1, const float* __restrict__ b1,
                             const float* __restrict__ w2, const float* __restrict__ b2,
                             const float* __restrict__ ln_g, const float* __restrict__ ln_b,
                             const float* __restrict__ ws, const float* __restrict__ bs,
                             const float* __restrict__ we, const float* __restrict__ be,
                             float* __restrict__ tabs) {
    const int v = blockIdx.x;
    const int t = threadIdx.x;        // 0..63
    __shared__ float sh_h[64];
    __shared__ float sh_a[128];
    __shared__ float sh_x[64];

    sh_h[t] = embed[v * 64 + t];
    __syncthreads();

    float acc0 = b1[t], acc1 = b1[t + 64];
    #pragma unroll 8
    for (int k = 0; k < 64; ++k) {
        const float hv = sh_h[k];
        acc0 += hv * w1[k * 128 + t];
        acc1 += hv * w1[k * 128 + t + 64];
    }
    sh_a[t]      = fmaxf(acc0, 0.f);
    sh_a[t + 64] = fmaxf(acc1, 0.f);
    __syncthreads();

    float x = sh_h[t] + b2[t];
    #pragma unroll 8
    for (int k = 0; k < 128; ++k) x += sh_a[k] * w2[k * 64 + t];

    float mu = x;
    for (int m = 1; m <= 32; m <<= 1) mu += __shfl_xor(mu, m);
    mu *= (1.f / 64.f);
    const float dx = x - mu;
    float var = dx * dx;
    for (int m = 1; m <= 32; m <<= 1) var += __shfl_xor(var, m);
    var *= (1.f / 64.f);
    const float hln = dx * rsqrtf(var + 1e-5f) * ln_g[t] + ln_b[t];
    sh_x[t] = hln;
    __syncthreads();

    const int j   = t & 31;
    const int mem = t >> 5;
    const float* W  = mem ? we : ws;
    const float* Bv = mem ? be : bs;
    float p = Bv[j];
    #pragma unroll 8
    for (int k = 0; k < 64; ++k) p += sh_x[k] * W[k * 32 + j];

    float nn = p * p;
    for (int m = 1; m <= 16; m <<= 1) nn += __shfl_xor(nn, m);
    const float kn = p / fmaxf(sqrtf(nn), 1e-12f);

    tabs[(mem * 64 + v) * 32 + j]        = kn;   // normalized key
    tabs[4096 + (mem * 64 + v) * 32 + j] = p;    // raw projection
}

// ---------------- Kernel A2: Gram tables -----------------------------------
__global__ void gram_kernel(const float* __restrict__ tabs, float* __restrict__ gout) {
    const int v  = blockIdx.x;
    const int tt = threadIdx.x;          // 0..127
    const int m  = tt >> 6, w = tt & 63;
    __shared__ float kv[64];
    if (tt < 64) kv[tt] = tabs[((tt >> 5) * 64 + v) * 32 + (tt & 31)];
    __syncthreads();
    const float* kw  = &tabs[(m * 64 + w) * 32];
    const float* kvm = &kv[m * 32];
    float acc = 0.f;
    #pragma unroll 8
    for (int j = 0; j < 32; ++j) acc += kvm[j] * kw[j];
    gout[m * 4096 + v * 64 + w] = acc;
}

// ---------------- Kernel B: dual-space scan + fused output -----------------
// grid 256 (batch), block 128 = 2 waves. wave 0: s-chain, wave 1: e-chain.
// lane (0..63) = vocab id v for gf / W.
__global__ void __launch_bounds__(128, 1) scan_kernel(const int* __restrict__ seq,
                                                      const float* __restrict__ tabs,
                                                      const float* __restrict__ wrp,
                                                      const float* __restrict__ brp,
                                                      const float* __restrict__ wout,
                                                      const float* __restrict__ bout,
                                                      float* __restrict__ out) {
    const int b    = blockIdx.x;
    const int tid  = threadIdx.x;        // 0..127
    const int m    = tid >> 6;           // wave id == chain id
    const int lane = tid & 63;           // vocab id v
    const int q    = lane & 31;

    __shared__ float gt [2 * 64 * 65];   // Gram rows padded to 65
    __shared__ float hsh[2 * 64 * 32];   // h tables [m][v][j]
    __shared__ float rsh[64];
    __shared__ float ysh[64];

    // ---- stage (one-time) ----
    for (int i = tid; i < 8192; i += 128) {
        const int mm = i >> 12, v = (i >> 6) & 63, ww = i & 63;
        gt[mm * 4160 + v * 65 + ww] = tabs[16384 + i];
    }
    for (int i = tid; i < 1024; i += 128)
        ((float4*)hsh)[i] = ((const float4*)(tabs + 4096))[i];
    __syncthreads();

    const int*  srow  = seq + b * L_SEQ;        // uniform base -> s_load
    const int   rowV  = m * 4160 + lane * 65;   // per-lane G row base
    const float invL  = 1.0f / (float)L_SEQ;
    const bool  mF    = (m != 0);
    const float invLe = mF ? invL : 0.0f;       // c step (0 for s-chain)

    // init: u = k_tokL  =>  gf_v = G[v][tokL]
    const int tokL = srow[NPOS];
    float gf = gt[rowV + tokL];
    float W  = 0.f;

    // ---- partial top block: positions 2046 .. 2016 (31 positions) ----
    {
        int tk[31]; float cgp[31];
        #pragma unroll
        for (int j = 0; j < 31; ++j) tk[j] = srow[2016 + j];
        const float cb = mF ? (float)(2016 + 1) * invL : 1.0f;
        #pragma unroll
        for (int j = 0; j < 31; ++j) {
            const float g = gt[rowV + tk[j]];
            const float c = cb + (float)j * invLe;
            cgp[j] = mF ? c * g : g;            // prescaled column
        }
        __builtin_amdgcn_sched_barrier(0);
        #pragma unroll
        for (int j = 30; j >= 0; --j) {
            const float d = rdlane(gf, tk[j]);
            gf = fmaf(-d, cgp[j], gf);          // chain: rdlane -> fmac only
            const float c = cb + (float)j * invLe;
            const float e = c * d;              // off-chain
            W += (lane == tk[j]) ? e : 0.f;
        }
    }

    // ---- main blocks: pb = 1984, 1952, ..., 0  (63 blocks x 32 positions) ----
    for (int pb = 1984; pb >= 0; pb -= 32) {
        if (__all(fabsf(gf) < 1e-4f)) break;    // residual-based exit (per wave)

        int tk[32]; float cgp[32];
        #pragma unroll
        for (int j = 0; j < 32; ++j) tk[j] = srow[pb + j];
        const float cb = mF ? (float)(pb + 1) * invL : 1.0f;
        #pragma unroll
        for (int j = 0; j < 32; ++j) {
            const float g = gt[rowV + tk[j]];
            const float c = cb + (float)j * invLe;
            cgp[j] = mF ? c * g : g;            // prescaled column
        }
        __builtin_amdgcn_sched_barrier(0);

        #pragma unroll
        for (int j = 31; j >= 0; --j) {
            const float d = rdlane(gf, tk[j]);
            gf = fmaf(-d, cgp[j], gf);          // chain: rdlane -> fmac only
            const float c = cb + (float)j * invLe;
            const float e = c * d;              // off-chain
            W += (lane == tk[j]) ? e : 0.f;
        }
    }

    // ---- r_q = sum_v W_v * h[v][q]  (both waves; lanes<32 valid) ----
    float r = 0.f;
    #pragma unroll 8
    for (int v = 0; v < 64; ++v) {
        const float wv = rdlane(W, v);
        r = fmaf(wv, hsh[(m * 64 + v) * 32 + q], r);
    }
    if (lane < 32) rsh[m * 32 + q] = r;         // [rs | re] concat order
    __syncthreads();

    // ---- fused output projection: out[b] = (r @ wrp + brp) @ wout + bout ----
    if (tid < 64) {
        float y = brp[tid];
        #pragma unroll 8
        for (int k = 0; k < 64; ++k) y += rsh[k] * wrp[k * 64 + tid];
        ysh[tid] = y;
    }
    __syncthreads();
    if (tid < 64) {
        float o = bout[tid];
        #pragma unroll 8
        for (int k = 0; k < 64; ++k) o += ysh[k] * wout[k * 64 + tid];
        out[b * 64 + tid] = o;
    }
}

// ---------------- launch ----------------------------------------------------
extern "C" void kernel_launch(void* const* d_in, const int* in_sizes, int n_in,
                              void* d_out, int out_size, void* d_ws, size_t ws_size,
                              hipStream_t stream) {
    const int*   seq   = (const int*)  d_in[0];
    const float* embed = (const float*)d_in[1];
    const float* w1    = (const float*)d_in[2];
    const float* b1    = (const float*)d_in[3];
    const float* w2    = (const float*)d_in[4];
    const float* b2    = (const float*)d_in[5];
    const float* ln_g  = (const float*)d_in[6];
    const float* ln_b  = (const float*)d_in[7];
    const float* ws    = (const float*)d_in[8];
    const float* bs    = (const float*)d_in[9];
    const float* we    = (const float*)d_in[10];
    const float* be    = (const float*)d_in[11];
    const float* wrp   = (const float*)d_in[12];
    const float* brp   = (const float*)d_in[13];
    const float* wout  = (const float*)d_in[14];
    const float* bout  = (const float*)d_in[15];

    float* tabs = (float*)d_ws;              // tables + gram
    float* gout = tabs + 16384;              // gram [2][64][64]

    build_tables<<<64, 64, 0, stream>>>(embed, w1, b1, w2, b2, ln_g, ln_b,
                                        ws, bs, we, be, tabs);
    gram_kernel<<<64, 128, 0, stream>>>(tabs, gout);
    scan_kernel<<<256, 128, 0, stream>>>(seq, tabs, wrp, brp, wout, bout,
                                         (float*)d_out);
}